// Round 5
// baseline (456.962 us; speedup 1.0000x reference)
//
#include <hip/hip_runtime.h>

#define N_COLS 8192

typedef float floatx4 __attribute__((ext_vector_type(4)));

// Kernel 1: single block, 1024 threads. Max-reduce x[0:8192], then write a
// dense float mask[8192] (1.0f where floor((x/max)*255) == t, else 0.0f) into
// workspace. Bit-exact div->mul->floorf chain (same as the verified kernels).
__global__ __launch_bounds__(1024) void spike_mask_kernel(const float* __restrict__ x,
                                                          const int* __restrict__ t_ptr,
                                                          float* __restrict__ mask) {
    __shared__ float smax[16];
    __shared__ float s_maxv;
    const int tid = threadIdx.x;  // 0..1023

    float vals[8];
    float m = -1e30f;
#pragma unroll
    for (int j = 0; j < 8; ++j) {
        vals[j] = x[tid + j * 1024];
        m = fmaxf(m, vals[j]);
    }
#pragma unroll
    for (int off = 32; off > 0; off >>= 1)
        m = fmaxf(m, __shfl_down(m, off, 64));
    if ((tid & 63) == 0) smax[tid >> 6] = m;
    __syncthreads();
    if (tid < 16) {
        float mm = smax[tid];
#pragma unroll
        for (int off = 8; off > 0; off >>= 1)
            mm = fmaxf(mm, __shfl_down(mm, off, 16));
        if (tid == 0) s_maxv = mm;
    }
    __syncthreads();

    const float maxv = s_maxv;
    const int t = *t_ptr;
#pragma unroll
    for (int j = 0; j < 8; ++j) {
        const int q = (int)floorf((vals[j] / maxv) * 255.0f);
        mask[tid + j * 1024] = (q == t) ? 1.0f : 0.0f;
    }
}

// Kernel 2: one-pass writer with the rocclr-fill access pattern.
// Grid-stride over 16,777,216 float4s with stride 524,288 (= 2048 blocks x
// 256 threads). Because 524,288 % 2048 == 0, each thread's column group
// (idx & 2047) is INVARIANT across its 32 iterations: load the 4 mask values
// once, branch once, then run a pure store loop. At every instant the whole
// grid writes one contiguous ~8 MiB window (identical aggregate pattern to
// __amd_rocclr_fillBufferAligned, which sustains 6.4 TB/s), unlike the
// round-1/3 column-tile walk (~1 TB/s). Weight is only fetched by the ~0.4%
// of lanes whose 4-column group contains a spike (exec-masked loads).
__global__ __launch_bounds__(256) void onepass_write_kernel(const float* __restrict__ w,
                                                            const float* __restrict__ mask,
                                                            float* __restrict__ out) {
    const floatx4* __restrict__ w4 = (const floatx4*)w;
    floatx4* __restrict__ o4 = (floatx4*)out;

    size_t idx = (size_t)blockIdx.x * 256 + threadIdx.x;   // float4 index
    const floatx4 mv = ((const floatx4*)mask)[idx & (N_COLS / 4 - 1)];
    const bool any = (mv.x != 0.0f) | (mv.y != 0.0f) | (mv.z != 0.0f) | (mv.w != 0.0f);

    if (any) {
        // rare path (~63% of waves have >=1 such lane; loads are exec-masked
        // so only spike lanes generate weight traffic)
#pragma unroll 8
        for (int i = 0; i < 32; ++i) {
            o4[idx] = w4[idx] * mv;     // mask is exactly 0.0/1.0
            idx += 524288;              // advance by the whole grid span
        }
    } else {
        const floatx4 z = {0.0f, 0.0f, 0.0f, 0.0f};
#pragma unroll 8
        for (int i = 0; i < 32; ++i) {
            o4[idx] = z;
            idx += 524288;
        }
    }
}

extern "C" void kernel_launch(void* const* d_in, const int* in_sizes, int n_in,
                              void* d_out, int out_size, void* d_ws, size_t ws_size,
                              hipStream_t stream) {
    const float* x = (const float*)d_in[0];   // [1, 8192] fp32
    const float* w = (const float*)d_in[1];   // [8192, 8192] fp32
    const int* t = (const int*)d_in[2];       // scalar int
    float* out = (float*)d_out;               // [8192, 8192] fp32
    float* mask = (float*)d_ws;               // [8192] fp32 spike mask

    // 1) Tiny: build the spike mask (one block, ~5 us).
    spike_mask_kernel<<<1, 1024, 0, stream>>>(x, t, mask);

    // 2) Single full-output pass: zeros everywhere, weight on spike columns.
    //    2048 blocks x 256 threads = 524,288 threads, 32 float4s each.
    onepass_write_kernel<<<2048, 256, 0, stream>>>(w, mask, out);
}

// Round 6
// 387.634 us; speedup vs baseline: 1.1788x; 1.1788x over previous
//
#include <hip/hip_runtime.h>

#define N_COLS 8192

typedef float floatx4 __attribute__((ext_vector_type(4)));

// Fused mask+scatter kernel. Grid = 256 blocks x 256 threads; block b owns
// rows [b*32, b*32+32). Each block independently:
//   1) loads all of x (32 KiB, L2-resident after the first block), computes
//      max(x) and the spike-column list into LDS — bit-exact div->mul->floorf
//      chain, identical to every verified round;
//   2) copies weight[r][c] -> out[r][c] for its 32 rows x spike columns.
// Launched AFTER the memset (stream-ordered), so non-spike columns stay 0.
// This removes the separate single-block spike kernel: ~8 us of serial node
// time becomes ~3 us of parallel per-block prologue.
__global__ __launch_bounds__(256) void fused_scatter_kernel(
        const float* __restrict__ x, const float* __restrict__ w,
        const int* __restrict__ t_ptr, float* __restrict__ out) {
    __shared__ int s_cols[N_COLS];     // worst case: every column spikes
    __shared__ float s_wmax[4];
    __shared__ int s_count;
    const int tid = threadIdx.x;       // 0..255
    if (tid == 0) s_count = 0;

    // ---- per-block max reduce over x[0..8191] ----
    const floatx4* __restrict__ x4 = (const floatx4*)x;
    floatx4 xv[8];
    float m = -1e30f;
#pragma unroll
    for (int k = 0; k < 8; ++k) {
        xv[k] = x4[tid + (k << 8)];    // coalesced; 256 thr x 8 = all 2048
        m = fmaxf(fmaxf(fmaxf(m, xv[k].x), fmaxf(xv[k].y, xv[k].z)), xv[k].w);
    }
#pragma unroll
    for (int off = 32; off > 0; off >>= 1)
        m = fmaxf(m, __shfl_down(m, off, 64));
    if ((tid & 63) == 0) s_wmax[tid >> 6] = m;
    __syncthreads();                   // also covers the s_count=0 write
    const float maxv = fmaxf(fmaxf(s_wmax[0], s_wmax[1]),
                             fmaxf(s_wmax[2], s_wmax[3]));

    // ---- spike-column list (LDS-compacted; order irrelevant) ----
    const int t = *t_ptr;
#pragma unroll
    for (int k = 0; k < 8; ++k) {
        const int c0 = (tid + (k << 8)) << 2;
        const float v[4] = {xv[k].x, xv[k].y, xv[k].z, xv[k].w};
#pragma unroll
        for (int j = 0; j < 4; ++j) {
            const int q = (int)floorf((v[j] / maxv) * 255.0f);
            if (q == t) s_cols[atomicAdd(&s_count, 1)] = c0 + j;
        }
    }
    __syncthreads();
    const int count = s_count;
    const int r0 = (int)blockIdx.x << 5;   // this block's first row

    // ---- copy 32 rows x count spike columns (spike weight == 1.0 exactly) ----
    const int pairs = count << 5;          // count * 32 rows
    for (int p = tid; p < pairs; p += 256) {
        const int k = p >> 5;              // spike-list index
        const int r = r0 + (p & 31);       // row within this block's band
        const long off = ((long)r << 13) + s_cols[k];
        out[off] = w[off];
    }
}

extern "C" void kernel_launch(void* const* d_in, const int* in_sizes, int n_in,
                              void* d_out, int out_size, void* d_ws, size_t ws_size,
                              hipStream_t stream) {
    const float* x = (const float*)d_in[0];   // [1, 8192] fp32
    const float* w = (const float*)d_in[1];   // [8192, 8192] fp32
    const int* t = (const int*)d_in[2];       // scalar int
    float* out = (float*)d_out;               // [8192, 8192] fp32

    // 1) Zero the output via the fast rocclr fill path (~6.4 TB/s, 42 us).
    //    out_size is already in bytes.
    hipMemsetAsync(out, 0, (size_t)out_size, stream);

    // 2) One kernel: per-block mask recompute + spike-column scatter.
    fused_scatter_kernel<<<256, 256, 0, stream>>>(x, w, t, out);
}